// Round 14
// baseline (122.016 us; speedup 1.0000x reference)
//
#include <hip/hip_runtime.h>

#define NB_MAX   512      // max 256-node buckets (n <= 131072)
#define CHUNK    4096     // edges per scatter block (= 8 * 512)
#define CAPB     16384    // slots per bucket region
#define SORT_CAP 6144     // LDS staging capacity per HALF-bucket (24KB)

__device__ inline unsigned short f2bf(float f) {   // round-to-nearest-even bf16
    unsigned u = __float_as_uint(f);
    u += 0x7FFFu + ((u >> 16) & 1u);
    return (unsigned short)(u >> 16);
}

// ---- zero d_out (G floats) and bcnt (NB_MAX ints) in one dispatch ----
__global__ void k_zero(float* __restrict__ out, int g, int* __restrict__ bcnt) {
    int t = blockIdx.x * blockDim.x + threadIdx.x;
    if (t < g) out[t] = 0.f;
    if (t < NB_MAX) bcnt[t] = 0;
}

// ---- pass 1: LDS bucket-sort each 4096-edge chunk (28KB LDS -> 4 blocks/CU);
//      edges register-cached (8/thread) so src/dst are read exactly once ----
__global__ __launch_bounds__(512) void k_scatter(const int* __restrict__ src,
                                                 const int* __restrict__ dst,
                                                 int* __restrict__ bcnt,
                                                 int* __restrict__ packed,
                                                 int E) {
    __shared__ int lh[NB_MAX];
    __shared__ int ldelta[NB_MAX];
    __shared__ int wsum[8];
    __shared__ int sorted[CHUNK];
    __shared__ unsigned short sbkt[CHUNK];
    int t = threadIdx.x;
    int e0 = blockIdx.x * CHUNK;
    int e1 = min(e0 + CHUNK, E);
    int cnt = e1 - e0;
    lh[t] = 0;
    __syncthreads();
    int pv[8], bv[8];
#pragma unroll
    for (int j = 0; j < 8; j++) {                   // hist + register cache
        int e = e0 + t + j * 512;
        bool ok = e < e1;
        int d = ok ? dst[e] : 0;
        int sv = ok ? src[e] : 0;
        int b = d >> 8;
        pv[j] = sv | ((d & 255) << 24);
        bv[j] = ok ? b : -1;
        if (ok) atomicAdd(&lh[b], 1);
    }
    __syncthreads();
    int v = lh[t];
    // wave-shfl inclusive scan over 512 elements (8 waves)
    int lane = t & 63, wid = t >> 6;
    int s = v;
#pragma unroll
    for (int o = 1; o < 64; o <<= 1) {
        int u = __shfl_up(s, o, 64);
        if (lane >= o) s += u;
    }
    if (lane == 63) wsum[wid] = s;
    __syncthreads();
    int base = 0;
#pragma unroll
    for (int w = 0; w < 8; w++) base += (w < wid) ? wsum[w] : 0;
    int ex = s + base - v;                          // exclusive prefix
    int gbase = v ? atomicAdd(&bcnt[t], v) : 0;     // reservation in bucket region
    lh[t] = ex;                                     // LDS sort cursor
    ldelta[t] = t * CAPB + gbase - ex;
    __syncthreads();
#pragma unroll
    for (int j = 0; j < 8; j++) {                   // sort from registers
        int b = bv[j];
        if (b >= 0) {
            int r = atomicAdd(&lh[b], 1);
            sorted[r] = pv[j];
            sbkt[r] = (unsigned short)b;
        }
    }
    __syncthreads();
    for (int i = t; i < cnt; i += 512)              // coalesced run writes
        packed[i + ldelta[sbkt[i]]] = sorted[i];
}

// ---- fused pass 2 + feature GEMM, TWO blocks per bucket (half = 128 nodes).
//      Each half-block reads the full bucket segment, hists/sorts only its
//      own dl-half; half-1 base = cnt - own_total (no extra atomics). ----
__global__ __launch_bounds__(512) void k_sortgemm(const int* __restrict__ packed,
                                                  const int* __restrict__ bcnt,
                                                  const float* __restrict__ x,
                                                  const float* __restrict__ W1,
                                                  int* __restrict__ sidx2,
                                                  int* __restrict__ noffs,
                                                  int* __restrict__ ndeg,
                                                  float* __restrict__ dinv,
                                                  unsigned short* __restrict__ hs,
                                                  int n) {
    __shared__ int hist[128];
    __shared__ int curs[128];
    __shared__ int wsum2[2];
    __shared__ int sh_ownbase, sh_owntot;
    __shared__ float sdinv[128];
    __shared__ float sW[128 * 16];                  // 8KB
    __shared__ __align__(16) char smem[SORT_CAP * 4];  // 24KB: sorted, then sXT
    int* sorted = (int*)smem;
    float* sXT = (float*)smem;                      // 32 x 132 floats (16.9KB)

    int t = threadIdx.x, blk = blockIdx.x;
    int b = blk >> 1, half = blk & 1;
    int seg0 = b * CAPB, cnt = bcnt[b];
    int node0h = blk << 7;                          // this block's 128 nodes

    // issue x loads for k-chunk 0 now: latency hides under sort phase
    float4 xreg[2];
#pragma unroll
    for (int pass = 0; pass < 2; pass++) {
        int row = pass * 64 + (t >> 3);
        xreg[pass] = *(const float4*)(x + (size_t)min(node0h + row, n - 1) * 128 + (t & 7) * 4);
    }
    for (int q = t; q < 2048; q += 512) sW[q] = W1[q];
    if (t < 128) hist[t] = 0;
    __syncthreads();
    int pv[16];
#pragma unroll
    for (int j = 0; j < 16; j++) {                  // full-segment read, own-half hist
        int e = t + j * 512;
        int p = (e < cnt) ? packed[seg0 + e] : 0;
        pv[j] = p;
        if (e < cnt) {
            int dl = (int)((unsigned)p >> 24);
            if ((dl >> 7) == half) atomicAdd(&hist[dl & 127], 1);
        }
    }
    for (int e = 8192 + t; e < cnt; e += 512) {     // rare tail
        int p = packed[seg0 + e];
        int dl = (int)((unsigned)p >> 24);
        if ((dl >> 7) == half) atomicAdd(&hist[dl & 127], 1);
    }
    __syncthreads();
    int v = 0, s = 0;
    int lane = t & 63, wid = t >> 6;
    if (t < 128) { v = hist[t]; s = v; }
#pragma unroll
    for (int o = 1; o < 64; o <<= 1) {
        int u = __shfl_up(s, o, 64);
        if (lane >= o) s += u;
    }
    if (t < 128 && lane == 63) wsum2[wid] = s;
    __syncthreads();
    if (t == 0) {
        int tot = wsum2[0] + wsum2[1];
        sh_owntot = tot;
        sh_ownbase = half ? (cnt - tot) : 0;
    }
    __syncthreads();
    int ownbase = sh_ownbase, owntot = sh_owntot;
    if (t < 128) {
        int base = (wid == 1) ? wsum2[0] : 0;
        int ex = s + base - v;                      // exclusive within own half
        curs[t] = ex;
        float di = rsqrtf((float)v + 1.0f);
        sdinv[t] = di;
        int node = node0h + t;
        if (node < n) {
            noffs[node] = seg0 + ownbase + ex;
            ndeg[node] = v;
            dinv[node] = di;
        }
    }
    __syncthreads();
    if (owntot <= SORT_CAP) {
#pragma unroll
        for (int j = 0; j < 16; j++) {              // sort own half from registers
            int e = t + j * 512;
            if (e < cnt) {
                int p = pv[j];
                int dl = (int)((unsigned)p >> 24);
                if ((dl >> 7) == half) {
                    int r = atomicAdd(&curs[dl & 127], 1);
                    sorted[r] = p & 0xFFFFFF;
                }
            }
        }
        for (int e = 8192 + t; e < cnt; e += 512) { // rare tail
            int p = packed[seg0 + e];
            int dl = (int)((unsigned)p >> 24);
            if ((dl >> 7) == half) {
                int r = atomicAdd(&curs[dl & 127], 1);
                sorted[r] = p & 0xFFFFFF;
            }
        }
        __syncthreads();
        for (int i = t; i < owntot; i += 512)       // coalesced streaming write
            sidx2[seg0 + ownbase + i] = sorted[i];
    } else {                                        // safety fallback (direct)
        for (int e = t; e < cnt; e += 512) {
            int p = packed[seg0 + e];
            int dl = (int)((unsigned)p >> 24);
            if ((dl >> 7) == half) {
                int r = atomicAdd(&curs[dl & 127], 1);
                sidx2[seg0 + ownbase + r] = p & 0xFFFFFF;
            }
        }
    }

    // ---- phase B: GEMM for 128 nodes; 1 node x 4 cols per thread ----
    int nd = t >> 2, cg = t & 3;
    float acc[4] = {0.f, 0.f, 0.f, 0.f};
    for (int kc = 0; kc < 4; kc++) {
        __syncthreads();                            // sorted dead / prev sXT consumed
#pragma unroll
        for (int pass = 0; pass < 2; pass++) {      // regs -> LDS (transposed)
            int row = pass * 64 + (t >> 3);
            int k0 = (t & 7) * 4;
            sXT[(k0 + 0) * 132 + row] = xreg[pass].x;
            sXT[(k0 + 1) * 132 + row] = xreg[pass].y;
            sXT[(k0 + 2) * 132 + row] = xreg[pass].z;
            sXT[(k0 + 3) * 132 + row] = xreg[pass].w;
        }
        if (kc < 3) {                               // issue next tile's loads
#pragma unroll
            for (int pass = 0; pass < 2; pass++) {
                int row = pass * 64 + (t >> 3);
                xreg[pass] = *(const float4*)(x + (size_t)min(node0h + row, n - 1) * 128
                                              + (kc + 1) * 32 + (t & 7) * 4);
            }
        }
        __syncthreads();
        const float* wb = sW + kc * 512 + cg * 4;
#pragma unroll 8
        for (int k = 0; k < 32; k++) {
            float xs = sXT[k * 132 + nd];
            float4 wv = *(const float4*)&wb[k * 16];
            acc[0] += xs * wv.x; acc[1] += xs * wv.y;
            acc[2] += xs * wv.z; acc[3] += xs * wv.w;
        }
    }
    int node = node0h + nd;
    if (node < n) {
        float di = sdinv[nd];
        ushort4 o;
        o.x = f2bf(acc[0] * di);
        o.y = f2bf(acc[1] * di);
        o.z = f2bf(acc[2] * di);
        o.w = f2bf(acc[3] * di);
        *(ushort4*)&hs[(size_t)node * 16 + cg * 4] = o;
    }
}

#define UNPACK_ADD2(u)                                       \
    acc[0] += __uint_as_float((u).x << 16);                  \
    acc[1] += __uint_as_float((u).x & 0xFFFF0000u);          \
    acc[2] += __uint_as_float((u).y << 16);                  \
    acc[3] += __uint_as_float((u).y & 0xFFFF0000u);

// ---- layer-1: CSR register-accumulate, 4 lanes/node (uint2 = 4 bf16 each),
//      8 gathers in flight ----
__global__ __launch_bounds__(256) void k_agg1(const uint2* __restrict__ hs2,
                                              const int* __restrict__ noffs,
                                              const int* __restrict__ ndeg,
                                              const int* __restrict__ sidx2,
                                              const float* __restrict__ dinv,
                                              const float* __restrict__ b1,
                                              const float* __restrict__ W2,
                                              float* __restrict__ hw, int n) {
    int tid = blockIdx.x * 256 + threadIdx.x;
    int node = tid >> 2, q = tid & 3;          // 4 lanes per node, 8B each
    if (node >= n) return;
    float acc[4];
    uint2 u0 = hs2[(size_t)node * 4 + q];      // self-loop row (pre-scaled)
    acc[0] = __uint_as_float(u0.x << 16);
    acc[1] = __uint_as_float(u0.x & 0xFFFF0000u);
    acc[2] = __uint_as_float(u0.y << 16);
    acc[3] = __uint_as_float(u0.y & 0xFFFF0000u);
    int e0 = noffs[node], e1 = e0 + ndeg[node];
    int e = e0;
    for (; e + 7 < e1; e += 8) {               // 8 gathers in flight
        int s0 = sidx2[e],     s1 = sidx2[e + 1];
        int s2 = sidx2[e + 2], s3 = sidx2[e + 3];
        int s4 = sidx2[e + 4], s5 = sidx2[e + 5];
        int s6 = sidx2[e + 6], s7 = sidx2[e + 7];
        uint2 a0 = hs2[(size_t)s0 * 4 + q];
        uint2 a1 = hs2[(size_t)s1 * 4 + q];
        uint2 a2 = hs2[(size_t)s2 * 4 + q];
        uint2 a3 = hs2[(size_t)s3 * 4 + q];
        uint2 a4 = hs2[(size_t)s4 * 4 + q];
        uint2 a5 = hs2[(size_t)s5 * 4 + q];
        uint2 a6 = hs2[(size_t)s6 * 4 + q];
        uint2 a7 = hs2[(size_t)s7 * 4 + q];
        UNPACK_ADD2(a0) UNPACK_ADD2(a1) UNPACK_ADD2(a2) UNPACK_ADD2(a3)
        UNPACK_ADD2(a4) UNPACK_ADD2(a5) UNPACK_ADD2(a6) UNPACK_ADD2(a7)
    }
    for (; e < e1; e++) {
        uint2 a = hs2[(size_t)sidx2[e] * 4 + q];
        UNPACK_ADD2(a)
    }
    float di = dinv[node];
    int base = q * 4;
    float r = 0.f;
#pragma unroll
    for (int j = 0; j < 4; j++)
        r += fmaxf(di * acc[j] + b1[base + j], 0.f) * W2[base + j];
    r += __shfl_down(r, 2, 4);
    r += __shfl_down(r, 1, 4);
    if (q == 0) hw[node] = r * di;              // pre-scaled for layer 2
}

// ---- layer-2: 2 lanes/node CSR accumulate + b2 + segmented pool ----
__global__ __launch_bounds__(256) void k_agg2(const float* __restrict__ hw,
                                              const int* __restrict__ noffs,
                                              const int* __restrict__ ndeg,
                                              const int* __restrict__ sidx2,
                                              const float* __restrict__ dinv,
                                              const float* __restrict__ b2,
                                              const int* __restrict__ batch,
                                              float* __restrict__ out, int n) {
    __shared__ float v[128];
    __shared__ int g[128];
    int t = threadIdx.x;
    int tid = blockIdx.x * 256 + t;
    int i = tid >> 1, q = tid & 1;
    int li = t >> 1;
    float acc = 0.f;
    int gid = -1;
    if (i < n) {
        if (q == 0) acc = hw[i];                // self-loop
        int e0 = noffs[i], e1 = e0 + ndeg[i];
        int e = e0 + q;
        for (; e + 6 < e1; e += 8)              // 4 gathers in flight per lane
            acc += hw[sidx2[e]] + hw[sidx2[e + 2]] + hw[sidx2[e + 4]] + hw[sidx2[e + 6]];
        for (; e < e1; e += 2) acc += hw[sidx2[e]];
    }
    acc += __shfl_down(acc, 1, 2);
    if (q == 0) {
        if (i < n) {
            v[li] = dinv[i] * acc + b2[0];
            g[li] = batch[i];
        } else {
            v[li] = 0.f;
            g[li] = -1;
        }
    }
    __syncthreads();
    if (q == 0) {
        int gid2 = g[li];
        if (gid2 >= 0 && (li == 0 || g[li - 1] != gid2)) {   // segment head
            float sum = v[li];
            for (int w = li + 1; w < 128 && g[w] == gid2; w++) sum += v[w];
            atomicAdd(&out[gid2], sum);
        }
    }
}

extern "C" void kernel_launch(void* const* d_in, const int* in_sizes, int n_in,
                              void* d_out, int out_size, void* d_ws, size_t ws_size,
                              hipStream_t stream) {
    int n = in_sizes[0] / 128;
    int E = in_sizes[1] / 2;
    const float* x     = (const float*)d_in[0];
    const int*   ei    = (const int*)d_in[1];
    const int*   src   = ei;
    const int*   dst   = ei + E;
    const int*   batch = (const int*)d_in[2];
    const float* W1    = (const float*)d_in[3];
    const float* b1    = (const float*)d_in[4];
    const float* W2    = (const float*)d_in[5];
    const float* b2    = (const float*)d_in[6];
    float* out = (float*)d_out;

    int nb = (n + 255) >> 8;            // 256-node buckets

    char* p = (char*)d_ws;
    auto carve = [&](size_t bytes) {
        void* r = (void*)p;
        p += (bytes + 63) & ~(size_t)63;
        return r;
    };
    int*            bcnt   = (int*)carve(NB_MAX * 4);
    int*            packed = (int*)carve((size_t)nb * CAPB * 4);
    int*            sidx2  = (int*)carve((size_t)nb * CAPB * 4);
    int*            noffs  = (int*)carve((size_t)n * 4);
    int*            ndeg   = (int*)carve((size_t)n * 4);
    float*          dinv   = (float*)carve((size_t)n * 4);
    unsigned short* hs     = (unsigned short*)carve((size_t)n * 16 * 2);
    float*          hw     = (float*)carve((size_t)n * 4);

    k_zero<<<(out_size + 1023) / 1024, 1024, 0, stream>>>(out, out_size, bcnt);
    k_scatter<<<(E + CHUNK - 1) / CHUNK, 512, 0, stream>>>(src, dst, bcnt, packed, E);
    k_sortgemm<<<2 * nb, 512, 0, stream>>>(packed, bcnt, x, W1, sidx2, noffs, ndeg,
                                           dinv, hs, n);
    k_agg1<<<((size_t)n * 4 + 255) / 256, 256, 0, stream>>>((const uint2*)hs, noffs, ndeg,
                                                            sidx2, dinv, b1, W2, hw, n);
    k_agg2<<<((size_t)n * 2 + 255) / 256, 256, 0, stream>>>(hw, noffs, ndeg, sidx2,
                                                            dinv, b2, batch, out, n);
}

// Round 15
// 114.457 us; speedup vs baseline: 1.0660x; 1.0660x over previous
//
#include <hip/hip_runtime.h>

#define NB_MAX   512      // max buckets (n <= 131072)
#define CHUNK    8192     // edges per scatter block (= 16 * 512)
#define CAPB     16384    // slots per bucket region
#define SORT_CAP 12288    // LDS staging capacity in k_sortgemm (48KB)

__device__ inline unsigned short f2bf(float f) {   // round-to-nearest-even bf16
    unsigned u = __float_as_uint(f);
    u += 0x7FFFu + ((u >> 16) & 1u);
    return (unsigned short)(u >> 16);
}

// ---- zero d_out (G floats) and bcnt (NB_MAX ints) in one dispatch ----
__global__ void k_zero(float* __restrict__ out, int g, int* __restrict__ bcnt) {
    int t = blockIdx.x * blockDim.x + threadIdx.x;
    if (t < g) out[t] = 0.f;
    if (t < NB_MAX) bcnt[t] = 0;
}

// ---- pass 1: LDS bucket-sort each chunk; edges register-cached (16/thread,
//      static index) so src/dst are read exactly once ----
__global__ __launch_bounds__(512) void k_scatter(const int* __restrict__ src,
                                                 const int* __restrict__ dst,
                                                 int* __restrict__ bcnt,
                                                 int* __restrict__ packed,
                                                 int E) {
    __shared__ int lh[NB_MAX];
    __shared__ int ldelta[NB_MAX];
    __shared__ int wsum[8];
    __shared__ int sorted[CHUNK];
    __shared__ unsigned short sbkt[CHUNK];
    int t = threadIdx.x;
    int e0 = blockIdx.x * CHUNK;
    int e1 = min(e0 + CHUNK, E);
    int cnt = e1 - e0;
    lh[t] = 0;
    __syncthreads();
    int pv[16], bv[16];
#pragma unroll
    for (int j = 0; j < 16; j++) {                  // hist + register cache
        int e = e0 + t + j * 512;
        bool ok = e < e1;
        int d = ok ? dst[e] : 0;
        int sv = ok ? src[e] : 0;
        int b = d >> 8;
        pv[j] = sv | ((d & 255) << 24);
        bv[j] = ok ? b : -1;
        if (ok) atomicAdd(&lh[b], 1);
    }
    __syncthreads();
    int v = lh[t];
    // wave-shfl inclusive scan over 512 elements (8 waves)
    int lane = t & 63, wid = t >> 6;
    int s = v;
#pragma unroll
    for (int o = 1; o < 64; o <<= 1) {
        int u = __shfl_up(s, o, 64);
        if (lane >= o) s += u;
    }
    if (lane == 63) wsum[wid] = s;
    __syncthreads();
    int base = 0;
#pragma unroll
    for (int w = 0; w < 8; w++) base += (w < wid) ? wsum[w] : 0;
    int ex = s + base - v;                          // exclusive prefix
    int gbase = v ? atomicAdd(&bcnt[t], v) : 0;     // reservation in bucket region
    lh[t] = ex;                                     // LDS sort cursor
    ldelta[t] = t * CAPB + gbase - ex;
    __syncthreads();
#pragma unroll
    for (int j = 0; j < 16; j++) {                  // sort from registers
        int b = bv[j];
        if (b >= 0) {
            int r = atomicAdd(&lh[b], 1);
            sorted[r] = pv[j];
            sbkt[r] = (unsigned short)b;
        }
    }
    __syncthreads();
    for (int i = t; i < cnt; i += 512)              // coalesced run writes
        packed[i + ldelta[sbkt[i]]] = sorted[i];
}

// ---- fused pass 2 + feature GEMM; packed register-cached, x reg-double-buffered ----
__global__ __launch_bounds__(512) void k_sortgemm(const int* __restrict__ packed,
                                                  const int* __restrict__ bcnt,
                                                  const float* __restrict__ x,
                                                  const float* __restrict__ W1,
                                                  int* __restrict__ sidx2,
                                                  int* __restrict__ noffs,
                                                  int* __restrict__ ndeg,
                                                  float* __restrict__ dinv,
                                                  unsigned short* __restrict__ hs,
                                                  int n) {
    __shared__ int hist[256];
    __shared__ int curs[256];
    __shared__ int wsum[4];
    __shared__ float sdinv[256];
    __shared__ float sW[128 * 16];                  // 8KB
    __shared__ __align__(16) char smem[SORT_CAP * 4];  // 48KB: sorted, then sXT
    int* sorted = (int*)smem;
    float* sXT = (float*)smem;                      // 32 x 260 floats

    int t = threadIdx.x, b = blockIdx.x;
    int seg0 = b * CAPB, cnt = bcnt[b];
    int node0 = b << 8;

    // issue x loads for k-chunk 0 immediately: latency hides under sort phase
    float4 xreg[4];
#pragma unroll
    for (int pass = 0; pass < 4; pass++) {
        int row = pass * 64 + (t >> 3);
        int node = node0 + row;
        xreg[pass] = *(const float4*)(x + (size_t)min(node, n - 1) * 128 + (t & 7) * 4);
    }

    for (int q = t; q < 2048; q += 512) sW[q] = W1[q];
    if (t < 256) hist[t] = 0;
    __syncthreads();
    int pv[16];
#pragma unroll
    for (int j = 0; j < 16; j++) {                  // hist + register cache (e < 8192)
        int e = t + j * 512;
        bool ok = e < cnt;
        int p = ok ? packed[seg0 + e] : 0;
        pv[j] = p;
        if (ok) atomicAdd(&hist[(unsigned)p >> 24], 1);
    }
    for (int e = CHUNK + t; e < cnt; e += 512)      // rare tail (cnt > 8192)
        atomicAdd(&hist[(unsigned)packed[seg0 + e] >> 24], 1);
    __syncthreads();
    int v = 0, s = 0;
    if (t < 256) { v = hist[t]; s = v; }
    int lane = t & 63, wid = t >> 6;
#pragma unroll
    for (int o = 1; o < 64; o <<= 1) {
        int u = __shfl_up(s, o, 64);
        if (lane >= o) s += u;
    }
    if (t < 256 && lane == 63) wsum[wid] = s;
    __syncthreads();
    int ex = 0;
    if (t < 256) {
        int base = 0;
#pragma unroll
        for (int w = 0; w < 4; w++) base += (w < wid) ? wsum[w] : 0;
        ex = s + base - v;                          // exclusive prefix in bucket
        float di = rsqrtf((float)v + 1.0f);
        sdinv[t] = di;
        int node = node0 + t;
        if (node < n) {
            noffs[node] = seg0 + ex;
            ndeg[node] = v;
            dinv[node] = di;
        }
    }
    if (cnt <= SORT_CAP) {
        if (t < 256) curs[t] = ex;
        __syncthreads();
#pragma unroll
        for (int j = 0; j < 16; j++) {              // sort from registers
            int e = t + j * 512;
            if (e < cnt) {
                int p = pv[j];
                int r = atomicAdd(&curs[(unsigned)p >> 24], 1);
                sorted[r] = p & 0xFFFFFF;
            }
        }
        for (int e = CHUNK + t; e < cnt; e += 512) {   // rare tail
            int p = packed[seg0 + e];
            int r = atomicAdd(&curs[(unsigned)p >> 24], 1);
            sorted[r] = p & 0xFFFFFF;
        }
        __syncthreads();
        for (int i = t; i < cnt; i += 512)          // coalesced streaming write
            sidx2[seg0 + i] = sorted[i];
    } else {                                        // safety fallback
        if (t < 256) curs[t] = seg0 + ex;
        __syncthreads();
        for (int e = t; e < cnt; e += 512) {
            int p = packed[seg0 + e];
            int dl = (int)((unsigned)p >> 24);
            int r = atomicAdd(&curs[dl], 1);
            sidx2[r] = p & 0xFFFFFF;
        }
    }

    // ---- phase B: GEMM, all 512 threads, 2x4 register tile;
    //      xreg holds tile kc while tile kc+1 loads fly ----
    int ng = t >> 2, cg = t & 3;        // 128 node-groups (2 nodes) x 4 col-groups
    float acc[2][4];
#pragma unroll
    for (int i = 0; i < 2; i++)
#pragma unroll
        for (int j = 0; j < 4; j++) acc[i][j] = 0.f;
    for (int kc = 0; kc < 4; kc++) {
        __syncthreads();                            // sorted dead / prev sXT consumed
#pragma unroll
        for (int pass = 0; pass < 4; pass++) {      // regs -> LDS
            int row = pass * 64 + (t >> 3);
            int k0 = (t & 7) * 4;
            sXT[(k0 + 0) * 260 + row] = xreg[pass].x;
            sXT[(k0 + 1) * 260 + row] = xreg[pass].y;
            sXT[(k0 + 2) * 260 + row] = xreg[pass].z;
            sXT[(k0 + 3) * 260 + row] = xreg[pass].w;
        }
        if (kc < 3) {                               // issue next tile's loads
#pragma unroll
            for (int pass = 0; pass < 4; pass++) {
                int row = pass * 64 + (t >> 3);
                int node = node0 + row;
                xreg[pass] = *(const float4*)(x + (size_t)min(node, n - 1) * 128
                                              + (kc + 1) * 32 + (t & 7) * 4);
            }
        }
        __syncthreads();
        const float* wbase = sW + kc * 32 * 16 + cg * 4;
#pragma unroll 8
        for (int k = 0; k < 32; k++) {
            float2 xv = *(const float2*)&sXT[k * 260 + ng * 2];
            float4 wv = *(const float4*)&wbase[k * 16];
            acc[0][0] += xv.x * wv.x; acc[0][1] += xv.x * wv.y;
            acc[0][2] += xv.x * wv.z; acc[0][3] += xv.x * wv.w;
            acc[1][0] += xv.y * wv.x; acc[1][1] += xv.y * wv.y;
            acc[1][2] += xv.y * wv.z; acc[1][3] += xv.y * wv.w;
        }
    }
#pragma unroll
    for (int i = 0; i < 2; i++) {
        int local = ng * 2 + i;
        int node = node0 + local;
        if (node < n) {
            float di = sdinv[local];
            ushort4 o;
            o.x = f2bf(acc[i][0] * di);
            o.y = f2bf(acc[i][1] * di);
            o.z = f2bf(acc[i][2] * di);
            o.w = f2bf(acc[i][3] * di);
            *(ushort4*)&hs[(size_t)node * 16 + cg * 4] = o;
        }
    }
}

#define UNPACK_ADD2(u)                                       \
    acc[0] += __uint_as_float((u).x << 16);                  \
    acc[1] += __uint_as_float((u).x & 0xFFFF0000u);          \
    acc[2] += __uint_as_float((u).y << 16);                  \
    acc[3] += __uint_as_float((u).y & 0xFFFF0000u);

// ---- layer-1: CSR register-accumulate, 4 lanes/node (uint2 = 4 bf16 each),
//      8 gathers in flight ----
__global__ __launch_bounds__(256) void k_agg1(const uint2* __restrict__ hs2,
                                              const int* __restrict__ noffs,
                                              const int* __restrict__ ndeg,
                                              const int* __restrict__ sidx2,
                                              const float* __restrict__ dinv,
                                              const float* __restrict__ b1,
                                              const float* __restrict__ W2,
                                              float* __restrict__ hw, int n) {
    int tid = blockIdx.x * 256 + threadIdx.x;
    int node = tid >> 2, q = tid & 3;          // 4 lanes per node, 8B each
    if (node >= n) return;
    float acc[4];
    uint2 u0 = hs2[(size_t)node * 4 + q];      // self-loop row (pre-scaled)
    acc[0] = __uint_as_float(u0.x << 16);
    acc[1] = __uint_as_float(u0.x & 0xFFFF0000u);
    acc[2] = __uint_as_float(u0.y << 16);
    acc[3] = __uint_as_float(u0.y & 0xFFFF0000u);
    int e0 = noffs[node], e1 = e0 + ndeg[node];
    int e = e0;
    for (; e + 7 < e1; e += 8) {               // 8 gathers in flight
        int s0 = sidx2[e],     s1 = sidx2[e + 1];
        int s2 = sidx2[e + 2], s3 = sidx2[e + 3];
        int s4 = sidx2[e + 4], s5 = sidx2[e + 5];
        int s6 = sidx2[e + 6], s7 = sidx2[e + 7];
        uint2 a0 = hs2[(size_t)s0 * 4 + q];
        uint2 a1 = hs2[(size_t)s1 * 4 + q];
        uint2 a2 = hs2[(size_t)s2 * 4 + q];
        uint2 a3 = hs2[(size_t)s3 * 4 + q];
        uint2 a4 = hs2[(size_t)s4 * 4 + q];
        uint2 a5 = hs2[(size_t)s5 * 4 + q];
        uint2 a6 = hs2[(size_t)s6 * 4 + q];
        uint2 a7 = hs2[(size_t)s7 * 4 + q];
        UNPACK_ADD2(a0) UNPACK_ADD2(a1) UNPACK_ADD2(a2) UNPACK_ADD2(a3)
        UNPACK_ADD2(a4) UNPACK_ADD2(a5) UNPACK_ADD2(a6) UNPACK_ADD2(a7)
    }
    for (; e < e1; e++) {
        uint2 a = hs2[(size_t)sidx2[e] * 4 + q];
        UNPACK_ADD2(a)
    }
    float di = dinv[node];
    int base = q * 4;
    float r = 0.f;
#pragma unroll
    for (int j = 0; j < 4; j++)
        r += fmaxf(di * acc[j] + b1[base + j], 0.f) * W2[base + j];
    r += __shfl_down(r, 2, 4);
    r += __shfl_down(r, 1, 4);
    if (q == 0) hw[node] = r * di;              // pre-scaled for layer 2
}

// ---- layer-2: 2 lanes/node CSR accumulate + b2 + segmented pool ----
__global__ __launch_bounds__(256) void k_agg2(const float* __restrict__ hw,
                                              const int* __restrict__ noffs,
                                              const int* __restrict__ ndeg,
                                              const int* __restrict__ sidx2,
                                              const float* __restrict__ dinv,
                                              const float* __restrict__ b2,
                                              const int* __restrict__ batch,
                                              float* __restrict__ out, int n) {
    __shared__ float v[128];
    __shared__ int g[128];
    int t = threadIdx.x;
    int tid = blockIdx.x * 256 + t;
    int i = tid >> 1, q = tid & 1;
    int li = t >> 1;
    float acc = 0.f;
    int gid = -1;
    if (i < n) {
        if (q == 0) acc = hw[i];                // self-loop
        int e0 = noffs[i], e1 = e0 + ndeg[i];
        int e = e0 + q;
        for (; e + 6 < e1; e += 8)              // 4 gathers in flight per lane
            acc += hw[sidx2[e]] + hw[sidx2[e + 2]] + hw[sidx2[e + 4]] + hw[sidx2[e + 6]];
        for (; e < e1; e += 2) acc += hw[sidx2[e]];
    }
    acc += __shfl_down(acc, 1, 2);
    if (q == 0) {
        if (i < n) {
            v[li] = dinv[i] * acc + b2[0];
            g[li] = batch[i];
        } else {
            v[li] = 0.f;
            g[li] = -1;
        }
    }
    __syncthreads();
    if (q == 0) {
        int gid2 = g[li];
        if (gid2 >= 0 && (li == 0 || g[li - 1] != gid2)) {   // segment head
            float sum = v[li];
            for (int w = li + 1; w < 128 && g[w] == gid2; w++) sum += v[w];
            atomicAdd(&out[gid2], sum);
        }
    }
}

extern "C" void kernel_launch(void* const* d_in, const int* in_sizes, int n_in,
                              void* d_out, int out_size, void* d_ws, size_t ws_size,
                              hipStream_t stream) {
    int n = in_sizes[0] / 128;
    int E = in_sizes[1] / 2;
    const float* x     = (const float*)d_in[0];
    const int*   ei    = (const int*)d_in[1];
    const int*   src   = ei;
    const int*   dst   = ei + E;
    const int*   batch = (const int*)d_in[2];
    const float* W1    = (const float*)d_in[3];
    const float* b1    = (const float*)d_in[4];
    const float* W2    = (const float*)d_in[5];
    const float* b2    = (const float*)d_in[6];
    float* out = (float*)d_out;

    int nb = (n + 255) >> 8;

    char* p = (char*)d_ws;
    auto carve = [&](size_t bytes) {
        void* r = (void*)p;
        p += (bytes + 63) & ~(size_t)63;
        return r;
    };
    int*            bcnt   = (int*)carve(NB_MAX * 4);
    int*            packed = (int*)carve((size_t)nb * CAPB * 4);
    int*            sidx2  = (int*)carve((size_t)nb * CAPB * 4);
    int*            noffs  = (int*)carve((size_t)n * 4);
    int*            ndeg   = (int*)carve((size_t)n * 4);
    float*          dinv   = (float*)carve((size_t)n * 4);
    unsigned short* hs     = (unsigned short*)carve((size_t)n * 16 * 2);
    float*          hw     = (float*)carve((size_t)n * 4);

    k_zero<<<(out_size + 1023) / 1024, 1024, 0, stream>>>(out, out_size, bcnt);
    k_scatter<<<(E + CHUNK - 1) / CHUNK, 512, 0, stream>>>(src, dst, bcnt, packed, E);
    k_sortgemm<<<nb, 512, 0, stream>>>(packed, bcnt, x, W1, sidx2, noffs, ndeg,
                                       dinv, hs, n);
    k_agg1<<<((size_t)n * 4 + 255) / 256, 256, 0, stream>>>((const uint2*)hs, noffs, ndeg,
                                                            sidx2, dinv, b1, W2, hw, n);
    k_agg2<<<((size_t)n * 2 + 255) / 256, 256, 0, stream>>>(hw, noffs, ndeg, sidx2,
                                                            dinv, b2, batch, out, n);
}